// Round 15
// baseline (692.084 us; speedup 1.0000x reference)
//
#include <hip/hip_runtime.h>
#include <hip/hip_bf16.h>
#include <math.h>

#define B_    2
#define S_    2048
#define D_    512
#define H_    8
#define DH_   64
#define M_    2048
#define L_    6

typedef float f4v __attribute__((ext_vector_type(4)));
typedef short s8v __attribute__((ext_vector_type(8)));
typedef unsigned short u16;
typedef unsigned short u16x4 __attribute__((ext_vector_type(4)));

// async global->LDS, 16B per lane; LDS dest is wave-uniform base + lane*16
#define GLOAD16(gp, lp) __builtin_amdgcn_global_load_lds( \
    (const __attribute__((address_space(1))) void*)(gp),  \
    (__attribute__((address_space(3))) void*)(lp), 16, 0, 0)

__device__ __forceinline__ unsigned pack2bf(float a, float b) {
    __hip_bfloat162 t;
    t.x = __float2bfloat16(a);
    t.y = __float2bfloat16(b);
    return *(unsigned*)&t;
}
__device__ __forceinline__ float bf2f(u16 u) {
    unsigned v = ((unsigned)u) << 16;
    return *(float*)&v;
}
__device__ __forceinline__ u16 f2bf(float f) {
    __hip_bfloat16 h = __float2bfloat16(f);
    return *(u16*)&h;
}

// ---------------------------------------------------------------------------
// Embedding + sinusoidal positional encoding + padding mask
// ---------------------------------------------------------------------------
__global__ __launch_bounds__(256) void embed_kernel(
    const int* __restrict__ tok, const float* __restrict__ emb,
    float* __restrict__ x, int* __restrict__ pad)
{
    int t = blockIdx.x;
    int s = t & (S_ - 1);
    int d = threadIdx.x;
    int tk = tok[t];
    if (d == 0) pad[t] = (tk > 0) ? 1 : 0;
    const float sf = -9.210340371976184f / 255.0f;
    float dt  = expf((float)d * sf);
    float ang = (float)s * dt;
    x[(size_t)t * D_ + d]       = emb[(size_t)tk * D_ + d]       + sinf(ang);
    x[(size_t)t * D_ + d + 256] = emb[(size_t)tk * D_ + d + 256] + cosf(ang);
}

// ---------------------------------------------------------------------------
// LayerNorm, wave-per-token: 256 threads = 4 waves = 4 tokens, grid NT/4.
// ---------------------------------------------------------------------------
template<bool OBF16>
__global__ __launch_bounds__(256) void ln_kernel(
    const float* __restrict__ xin, const float* __restrict__ sc,
    const float* __restrict__ bi, void* __restrict__ yout)
{
    const int wave = threadIdx.x >> 6, lane = threadIdx.x & 63;
    const int t = blockIdx.x * 4 + wave;
    const float* row = xin + (size_t)t * D_;
    f4v a = *(const f4v*)&row[lane * 4];
    f4v b = *(const f4v*)&row[256 + lane * 4];
    float ssum = a.x + a.y + a.z + a.w + b.x + b.y + b.z + b.w;
    float ssq  = a.x*a.x + a.y*a.y + a.z*a.z + a.w*a.w
               + b.x*b.x + b.y*b.y + b.z*b.z + b.w*b.w;
    #pragma unroll
    for (int m = 32; m; m >>= 1) {
        ssum += __shfl_xor(ssum, m);
        ssq  += __shfl_xor(ssq,  m);
    }
    float mu  = ssum * (1.0f / D_);
    float var = ssq * (1.0f / D_) - mu * mu;
    float r   = rsqrtf(var + 1e-6f);
    f4v sa = *(const f4v*)&sc[lane * 4];
    f4v sb = *(const f4v*)&sc[256 + lane * 4];
    f4v ba = *(const f4v*)&bi[lane * 4];
    f4v bb = *(const f4v*)&bi[256 + lane * 4];
    f4v oa, ob2;
    oa.x = (a.x - mu) * r * sa.x + ba.x;  oa.y = (a.y - mu) * r * sa.y + ba.y;
    oa.z = (a.z - mu) * r * sa.z + ba.z;  oa.w = (a.w - mu) * r * sa.w + ba.w;
    ob2.x = (b.x - mu) * r * sb.x + bb.x; ob2.y = (b.y - mu) * r * sb.y + bb.y;
    ob2.z = (b.z - mu) * r * sb.z + bb.z; ob2.w = (b.w - mu) * r * sb.w + bb.w;
    if (OBF16) {
        u16* y = (u16*)yout + (size_t)t * D_;
        u16x4 pa, pb;
        pa.x = f2bf(oa.x); pa.y = f2bf(oa.y); pa.z = f2bf(oa.z); pa.w = f2bf(oa.w);
        pb.x = f2bf(ob2.x); pb.y = f2bf(ob2.y); pb.z = f2bf(ob2.z); pb.w = f2bf(ob2.w);
        *(u16x4*)&y[lane * 4] = pa;
        *(u16x4*)&y[256 + lane * 4] = pb;
    } else {
        float* y = (float*)yout + (size_t)t * D_;
        *(f4v*)&y[lane * 4] = oa;
        *(f4v*)&y[256 + lane * 4] = ob2;
    }
}

// ---------------------------------------------------------------------------
// Weight transpose + cast: W[K][N] f32 -> Wt[N][K] bf16, all 6 layers.
// ---------------------------------------------------------------------------
__global__ __launch_bounds__(256) void transpose_cast(
    const float* __restrict__ wq, const float* __restrict__ wk,
    const float* __restrict__ wv, const float* __restrict__ wo,
    const float* __restrict__ w1, const float* __restrict__ w2,
    __hip_bfloat16* __restrict__ dst)
{
    __shared__ float tile[32][33];
    const int l = blockIdx.y;
    const int bx = blockIdx.x;
    const size_t lbase = (size_t)l * 3145728;
    const float* src; __hip_bfloat16* d; int K, N, kt, nt;
    float wscale = 1.0f;
    if (bx < 1024) {
        int m = bx >> 8, t = bx & 255;
        const float* s4 = (m == 0) ? wq : (m == 1) ? wk : (m == 2) ? wv : wo;
        if (m == 0) wscale = 0.125f;
        src = s4 + (size_t)l * 262144;
        d = dst + lbase + (size_t)m * 262144;
        K = 512; N = 512; kt = t >> 4; nt = t & 15;
    } else if (bx < 2048) {
        int t = bx - 1024;
        src = w1 + (size_t)l * 1048576;
        d = dst + lbase + 1048576;
        K = 512; N = 2048; kt = t >> 6; nt = t & 63;
    } else {
        int t = bx - 2048;
        src = w2 + (size_t)l * 1048576;
        d = dst + lbase + 2097152;
        K = 2048; N = 512; kt = t >> 4; nt = t & 15;
    }
    const int x = threadIdx.x & 31, y = threadIdx.x >> 5;
    const int kk0 = kt * 32, nn0 = nt * 32;
    #pragma unroll
    for (int p = 0; p < 4; ++p)
        tile[y + p * 8][x] = src[(size_t)(kk0 + y + p * 8) * N + nn0 + x];
    __syncthreads();
    #pragma unroll
    for (int p = 0; p < 4; ++p)
        d[(size_t)(nn0 + y + p * 8) * K + kk0 + x] =
            __float2bfloat16(tile[x][y + p * 8] * wscale);
}

// ---------------------------------------------------------------------------
// fast tanh-GELU
// ---------------------------------------------------------------------------
__device__ __forceinline__ float gelu_tanh(float xx) {
    float u = fminf(fmaxf(xx, -10.f), 10.f);
    float t = 0.7978845608028654f * (u + 0.044715f * u * u * u);
    float e = __expf(2.f * t);
    float th = 1.f - 2.f * __builtin_amdgcn_rcpf(e + 1.f);
    return 0.5f * xx * (1.f + th);
}

// ---------------------------------------------------------------------------
// Single-K-group GEMM, 256 threads (4 waves), 128x64 block tile, wave C-tile
// 64x32, BK=32, 4-buffer 3-deep pipeline, ONE barrier per K-step.
// With 4 bufs, tile t+3 lands in buf (t+3)&3 = (t-1)&3 whose readers all
// finished before crossing this step's barrier (their ds_reads complete
// before MFMA issue, which precedes the barrier) -> the release
// lgkmcnt(0)+barrier of the 3-buf scheme is deleted. Prefetch issued between
// ds_read and MFMA (T14 issue-early). vmcnt schedule unchanged: 6/3/0.
// LDS 48KB -> 3 blocks/CU. For QKV (768) and MLP1 (1024).
// ---------------------------------------------------------------------------
template<bool OUT_BF16, int TAG>
__global__ __launch_bounds__(256) void gemm_1g(
    const __hip_bfloat16* __restrict__ A, const __hip_bfloat16* __restrict__ Wt,
    const float* __restrict__ bias, const float* __restrict__ resid,
    void* __restrict__ Cout, int K, int ldc, int ncol, int gelu)
{
    __shared__ __align__(16) char lds[49152];   // 4 bufs x 12KB

    const int nwg = gridDim.x;
    const int cpx = nwg >> 3;
    const int bid = blockIdx.x;
    const int pos = (bid & 7) * cpx + (bid >> 3);
    const int row0 = (pos / ncol) * 128;
    const int col0 = (pos % ncol) * 64;

    const int tid = threadIdx.x, lane = tid & 63, wg = tid >> 6;  // 4 waves
    const int wr = wg >> 1, wc = wg & 1;
    const int lq = lane & 15, g = lane >> 4;

    const int nt = K >> 5;
    const char* Ab = (const char*)A;
    const char* Bt = (const char*)Wt;
    const int ldsrow = lane >> 2;
    const int swzseg = (lane & 3) ^ ((lane >> 3) & 3);
    const int slot8  = (g ^ ((lq >> 1) & 3)) * 8;

    f4v acc[4][2] = {};

    auto STAGE = [&](int c, int t) {
        const int k0 = t * 32;
        char* dst = lds + c * 12288;
        #pragma unroll
        for (int i2 = 0; i2 < 2; ++i2) {
            int seg = wg * 2 + i2;
            const char* gp = Ab + ((size_t)(row0 + seg * 16 + ldsrow) * K + k0) * 2 + swzseg * 16;
            GLOAD16(gp, dst + seg * 1024);
        }
        {
            const char* gp = Bt + ((size_t)(col0 + wg * 16 + ldsrow) * K + k0) * 2 + swzseg * 16;
            GLOAD16(gp, dst + 8192 + wg * 1024);
        }
    };

    STAGE(0, 0);
    STAGE(1, 1);
    STAGE(2, 2);

    for (int t = 0; t < nt; ++t) {
        if (t < nt - 2)      asm volatile("s_waitcnt vmcnt(6)" ::: "memory");
        else if (t < nt - 1) asm volatile("s_waitcnt vmcnt(3)" ::: "memory");
        else                 asm volatile("s_waitcnt vmcnt(0)" ::: "memory");
        __builtin_amdgcn_s_barrier();
        __builtin_amdgcn_sched_barrier(0);

        const unsigned short* Al = (const unsigned short*)(lds + (t & 3) * 12288);
        const unsigned short* Bl = Al + 4096;
        s8v af[4], bfv[2];
        #pragma unroll
        for (int mi = 0; mi < 4; ++mi)
            af[mi] = *(const s8v*)&Al[(wr * 64 + mi * 16 + lq) * 32 + slot8];
        #pragma unroll
        for (int ni = 0; ni < 2; ++ni)
            bfv[ni] = *(const s8v*)&Bl[(wc * 32 + ni * 16 + lq) * 32 + slot8];

        if (t + 3 < nt) STAGE((t + 3) & 3, t + 3);   // issue-early prefetch

        __builtin_amdgcn_s_setprio(1);
        #pragma unroll
        for (int mi = 0; mi < 4; ++mi)
            #pragma unroll
            for (int ni = 0; ni < 2; ++ni)
                acc[mi][ni] = __builtin_amdgcn_mfma_f32_16x16x32_bf16(af[mi], bfv[ni], acc[mi][ni], 0, 0, 0);
        __builtin_amdgcn_s_setprio(0);
    }

    #pragma unroll
    for (int mi = 0; mi < 4; ++mi) {
        #pragma unroll
        for (int ni = 0; ni < 2; ++ni) {
            #pragma unroll
            for (int jj = 0; jj < 4; ++jj) {
                int rrow = row0 + wr * 64 + mi * 16 + g * 4 + jj;
                int ccol = col0 + wc * 32 + ni * 16 + lq;
                float vv = acc[mi][ni][jj];
                if (bias)  vv += bias[ccol];
                if (gelu)  vv = gelu_tanh(vv);
                if (resid) vv += resid[(size_t)rrow * ldc + ccol];
                if (OUT_BF16)
                    ((__hip_bfloat16*)Cout)[(size_t)rrow * ldc + ccol] = __float2bfloat16(vv);
                else
                    ((float*)Cout)[(size_t)rrow * ldc + ccol] = vv;
            }
        }
    }
}

// ---------------------------------------------------------------------------
// Split-K2 GEMM, BK=64 per step — for the grid-256 (1 block/CU) GEMMs
// (o-proj, MLP2). (round-10 proven)
// ---------------------------------------------------------------------------
template<bool OUT_BF16, int TAG>
__global__ __launch_bounds__(512) void gemm_bk64(
    const __hip_bfloat16* __restrict__ A, const __hip_bfloat16* __restrict__ Wt,
    const float* __restrict__ bias, const float* __restrict__ resid,
    void* __restrict__ Cout, int K, int ldc, int ncol, int gelu)
{
    __shared__ __align__(16) char lds[147456];

    const int nwg = gridDim.x;
    const int cpx = nwg >> 3;
    const int bid = blockIdx.x;
    const int pos = (bid & 7) * cpx + (bid >> 3);
    const int row0 = (pos / ncol) * 128;
    const int col0 = (pos % ncol) * 64;

    const int tid = threadIdx.x, lane = tid & 63, w = tid >> 6;
    const int kg = w >> 2, wg = w & 3;
    const int wr = wg >> 1, wc = wg & 1;
    const int lq = lane & 15, g = lane >> 4;

    const int Kpart = K >> 1;
    const int nt = Kpart >> 6;
    const char* Ab = (const char*)A;
    const char* Bt = (const char*)Wt;
    const int srow8  = lane >> 3;
    const int schunk = lane & 7;
    const int gchunk = schunk ^ srow8;

    f4v acc[4][2] = {};

    auto STAGE = [&](int c, int t) {
        const int k0 = kg * Kpart + t * 64;
        char* dst = lds + (kg * 3 + c) * 24576;
        #pragma unroll
        for (int i2 = 0; i2 < 4; ++i2) {
            int seg = wg * 4 + i2;
            const char* gp = Ab + ((size_t)(row0 + seg * 8 + srow8) * K + k0) * 2 + gchunk * 16;
            GLOAD16(gp, dst + seg * 1024);
        }
        #pragma unroll
        for (int i2 = 0; i2 < 2; ++i2) {
            int seg = wg * 2 + i2;
            const char* gp = Bt + ((size_t)(col0 + seg * 8 + srow8) * K + k0) * 2 + gchunk * 16;
            GLOAD16(gp, dst + 16384 + seg * 1024);
        }
    };

    STAGE(0, 0);
    STAGE(1, 1);
    STAGE(2, 2);

    for (int t = 0; t < nt; ++t) {
        if (t < nt - 2)      asm volatile("s_waitcnt vmcnt(12)" ::: "memory");
        else if (t < nt - 1) asm volatile("s_waitcnt vmcnt(6)" ::: "memory");
        else                 asm volatile("s_waitcnt vmcnt(0)" ::: "memory");
        __builtin_amdgcn_s_barrier();
        __builtin_amdgcn_sched_barrier(0);

        const unsigned short* Al = (const unsigned short*)(lds + (kg * 3 + t % 3) * 24576);
        const unsigned short* Bl = Al + 8192;
        s8v af[4][2], bfv[2][2];
        #pragma unroll
        for (int ks = 0; ks < 2; ++ks) {
            #pragma unroll
            for (int mi = 0; mi < 4; ++mi) {
                const int r = wr * 64 + mi * 16 + lq;
                af[mi][ks] = *(const s8v*)&Al[r * 64 + (((ks * 4 + g) ^ (r & 7)) * 8)];
            }
            #pragma unroll
            for (int ni = 0; ni < 2; ++ni) {
                const int r = wc * 32 + ni * 16 + lq;
                bfv[ni][ks] = *(const s8v*)&Bl[r * 64 + (((ks * 4 + g) ^ (r & 7)) * 8)];
            }
        }

        __builtin_amdgcn_s_setprio(1);
        #pragma unroll
        for (int ks = 0; ks < 2; ++ks)
            #pragma unroll
            for (int mi = 0; mi < 4; ++mi)
                #pragma unroll
                for (int ni = 0; ni < 2; ++ni)
                    acc[mi][ni] = __builtin_amdgcn_mfma_f32_16x16x32_bf16(af[mi][ks], bfv[ni][ks], acc[mi][ni], 0, 0, 0);
        __builtin_amdgcn_s_setprio(0);

        asm volatile("s_waitcnt lgkmcnt(0)" ::: "memory");
        __builtin_amdgcn_s_barrier();
        __builtin_amdgcn_sched_barrier(0);
        if (t + 3 < nt) STAGE(t % 3, t + 3);
    }

    float* scr = (float*)lds;
    if (kg == 1) {
        #pragma unroll
        for (int mi = 0; mi < 4; ++mi)
            #pragma unroll
            for (int ni = 0; ni < 2; ++ni)
                *(f4v*)&scr[(((mi * 2 + ni) * 4 + wg) * 64 + lane) * 4] = acc[mi][ni];
    }
    __syncthreads();
    if (kg == 1) return;

    #pragma unroll
    for (int mi = 0; mi < 4; ++mi)
        #pragma unroll
        for (int ni = 0; ni < 2; ++ni)
            acc[mi][ni] += *(const f4v*)&scr[(((mi * 2 + ni) * 4 + wg) * 64 + lane) * 4];

    #pragma unroll
    for (int mi = 0; mi < 4; ++mi) {
        #pragma unroll
        for (int ni = 0; ni < 2; ++ni) {
            #pragma unroll
            for (int jj = 0; jj < 4; ++jj) {
                int rrow = row0 + wr * 64 + mi * 16 + g * 4 + jj;
                int ccol = col0 + wc * 32 + ni * 16 + lq;
                float vv = acc[mi][ni][jj];
                if (bias)  vv += bias[ccol];
                if (gelu)  vv = gelu_tanh(vv);
                if (resid) vv += resid[(size_t)rrow * ldc + ccol];
                if (OUT_BF16)
                    ((__hip_bfloat16*)Cout)[(size_t)rrow * ldc + ccol] = __float2bfloat16(vv);
                else
                    ((float*)Cout)[(size_t)rrow * ldc + ccol] = vv;
            }
        }
    }
}

// ---------------------------------------------------------------------------
// MFMA sliding-window attention, Q-tile 128, 8 waves, 64-key double-buffered
// chunks; async-stage split (T14). All qkv data bf16. (round-13 best)
// ---------------------------------------------------------------------------
__global__ __launch_bounds__(512) void attn_mfma_kernel(
    const u16* __restrict__ qkv, const int* __restrict__ pad,
    __hip_bfloat16* __restrict__ o)
{
    __shared__ __align__(16) unsigned short Klds[2][64 * 64];
    __shared__ __align__(16) unsigned short Vt[2][64 * 64];
    __shared__ float padfa[640];

    const int qt = blockIdx.x, bh = blockIdx.y;
    const int h = bh & 7, b = bh >> 3;
    const int q0 = qt * 128;
    const int tid = threadIdx.x, w = tid >> 6, lane = tid & 63;
    const int lq = lane & 15, g = lane >> 4;
    const int wq0 = q0 + w * 16;
    const size_t base = (size_t)b * S_ * 1536 + h * 64;

    for (int j = tid; j < 640; j += 512) {
        int krow = q0 - 256 + j;
        padfa[j] = (krow >= 0 && krow < S_ && pad[b * S_ + krow] != 0) ? 1.f : 0.f;
    }

    s8v qf[2];
    {
        const u16* qr = qkv + base + (size_t)(wq0 + lq) * 1536;
        #pragma unroll
        for (int ks = 0; ks < 2; ++ks)
            qf[ks] = *(const s8v*)&qr[ks * 32 + g * 8];
    }

    float lsum = 0.f;
    f4v oacc[4] = {};
    const int oblane = 256 + 4 * g - wq0 - lq;

    const int ki = tid >> 3, kss = tid & 7;
    const int vd = tid & 63, vkb = tid >> 6;
    s8v kreg;
    u16 vreg0, vreg1, vreg2, vreg3, vreg4, vreg5, vreg6, vreg7;

    auto LOAD_REGS = [&](int c) {
        const int kc = q0 - 256 + c * 64;
        {
            int krow = kc + ki;
            int kcl = krow < 0 ? 0 : (krow >= S_ ? S_ - 1 : krow);
            kreg = *(const s8v*)&qkv[base + 512 + (size_t)kcl * 1536 + kss * 8];
        }
        {
            int kr0 = kc + vkb * 8;
            const u16* vp = qkv + base + 1024 + vd;
            int c0 = kr0+0 < 0 ? 0 : (kr0+0 >= S_ ? S_-1 : kr0+0);
            int c1 = kr0+1 < 0 ? 0 : (kr0+1 >= S_ ? S_-1 : kr0+1);
            int c2 = kr0+2 < 0 ? 0 : (kr0+2 >= S_ ? S_-1 : kr0+2);
            int c3 = kr0+3 < 0 ? 0 : (kr0+3 >= S_ ? S_-1 : kr0+3);
            int c4 = kr0+4 < 0 ? 0 : (kr0+4 >= S_ ? S_-1 : kr0+4);
            int c5 = kr0+5 < 0 ? 0 : (kr0+5 >= S_ ? S_-1 : kr0+5);
            int c6 = kr0+6 < 0 ? 0 : (kr0+6 >= S_ ? S_-1 : kr0+6);
            int c7 = kr0+7 < 0 ? 0 : (kr0+7 >= S_ ? S_-1 : kr0+7);
            vreg0 = vp[(size_t)c0 * 1536]; vreg1 = vp[(size_t)c1 * 1536];
            vreg2 = vp[(size_t)c2 * 1536]; vreg3 = vp[(size_t)c3 * 1536];
            vreg4 = vp[(size_t)c4 * 1536]; vreg5 = vp[(size_t)c5 * 1536];
            vreg6 = vp[(size_t)c6 * 1536]; vreg7 = vp[(size_t)c7 * 1536];
        }
    };
    auto WRITE_LDS = [&](int buf) {
        *(s8v*)&Klds[buf][ki * 64 + ((kss ^ (ki & 7)) * 8)] = kreg;
        union { s8v s; u16 u[8]; } vv;
        vv.u[0] = vreg0; vv.u[1] = vreg1; vv.u[2] = vreg2; vv.u[3] = vreg3;
        vv.u[4] = vreg4; vv.u[5] = vreg5; vv.u[6] = vreg6; vv.u[7] = vreg7;
        *(s8v*)&Vt[buf][vd * 64 + ((vkb ^ (vd & 7)) * 8)] = vv.s;
    };

    LOAD_REGS(0);
    WRITE_LDS(0);
    LOAD_REGS(1);

    #pragma unroll 1
    for (int c = 0; c < 10; ++c) {
        asm volatile("s_waitcnt lgkmcnt(0)" ::: "memory");
        __builtin_amdgcn_s_barrier();
        __builtin_amdgcn_sched_barrier(0);
        const int kc = q0 - 256 + c * 64;
        const int buf = c & 1;

        #pragma unroll
        for (int sub = 0; sub < 2; ++sub) {
            const int kc2 = kc + sub * 32;
            if (kc2 + 31 < wq0 - 256 || kc2 > wq0 + 271) continue;

            f4v st[2] = {};
            __builtin_amdgcn_s_setprio(1);
            #pragma unroll
            for (int tt = 0; tt < 2; ++tt) {
                #pragma unroll
                for (int ks = 0; ks < 2; ++ks) {
                    const int row = sub * 32 + tt * 16 + lq;
                    const s8v af = *(const s8v*)&Klds[buf][row * 64 + (((ks * 4 + g) ^ (row & 7)) * 8)];
                    st[tt] = __builtin_amdgcn_mfma_f32_16x16x32_bf16(af, qf[ks], st[tt], 0, 0, 0);
                }
            }
            __builtin_amdgcn_s_setprio(0);

            float psum = 0.f;
            unsigned wpk[2][2];
            #pragma unroll
            for (int tt = 0; tt < 2; ++tt) {
                float pr[4];
                #pragma unroll
                for (int r = 0; r < 4; ++r) {
                    const int off = kc2 + 16 * tt + r + oblane;
                    float e = __expf(fminf(st[tt][r], 60.f)) *
                              padfa[c * 64 + sub * 32 + 16 * tt + 4 * g + r];
                    pr[r] = ((unsigned)off <= 512u) ? e : 0.f;
                    psum += pr[r];
                }
                wpk[tt][0] = pack2bf(pr[0], pr[1]);
                wpk[tt][1] = pack2bf(pr[2], pr[3]);
            }
            psum += __shfl_xor(psum, 16);
            psum += __shfl_xor(psum, 32);
            lsum += psum;

            const int srcA = (((2 * g) & 3) * 16 + lq) << 2;
            const int srcB = (((2 * g + 1) & 3) * 16 + lq) << 2;
            const bool hi = (g >= 2);
            union { s8v s; int u[4]; } pa;
            {
                int a0 = __builtin_amdgcn_ds_bpermute(srcA, (int)wpk[0][0]);
                int a1 = __builtin_amdgcn_ds_bpermute(srcA, (int)wpk[1][0]);
                pa.u[0] = hi ? a1 : a0;
                int b0 = __builtin_amdgcn_ds_bpermute(srcA, (int)wpk[0][1]);
                int b1 = __builtin_amdgcn_ds_bpermute(srcA, (int)wpk[1][1]);
                pa.u[1] = hi ? b1 : b0;
                int c0 = __builtin_amdgcn_ds_bpermute(srcB, (int)wpk[0][0]);
                int c1 = __builtin_amdgcn_ds_bpermute(srcB, (int)wpk[1][0]);
                pa.u[2] = hi ? c1 : c0;
                int d0 = __builtin_amdgcn_ds_bpermute(srcB, (int)wpk[0][1]);
                int d1 = __builtin_amdgcn_ds_bpermute(srcB, (int)wpk[1][1]);
                pa.u[3] = hi ? d1 : d0;
            }

            __builtin_amdgcn_s_setprio(1);
            #pragma unroll
            for (int dt = 0; dt < 4; ++dt) {
                const int row = dt * 16 + lq;
                const s8v vf = *(const s8v*)&Vt[buf][row * 64 + (((sub * 4 + g) ^ (row & 7)) * 8)];
                oacc[dt] = __builtin_amdgcn_mfma_f32_16x16x32_bf16(pa.s, vf, oacc[dt], 0, 0, 0);
            }
            __builtin_amdgcn_s_setprio(0);
        }

        if (c + 1 < 10) WRITE_LDS((c + 1) & 1);
        if (c + 2 < 10) LOAD_REGS(c + 2);
    }

    float inv = 1.0f / lsum;
    #pragma unroll
    for (int r = 0; r < 4; ++r) {
        int iv = __builtin_amdgcn_ds_bpermute((4 * g + r) << 2, __float_as_int(inv));
        float invq = __int_as_float(iv);
        const int qq = wq0 + 4 * g + r;
        __hip_bfloat16* orow = o + ((size_t)b * S_ + qq) * 512 + h * 64;
        #pragma unroll
        for (int dt = 0; dt < 4; ++dt)
            orow[dt * 16 + lq] = __float2bfloat16(oacc[dt][r] * invq);
    }

    // rare path: pad[q]==0 -> plain softmax over ALL S keys (overwrites)
    {
        int padq = pad[b * S_ + wq0 + lq];
        unsigned long long bal = __ballot(g == 0 && padq == 0);
        if (bal) {
            #pragma unroll 1
            for (int r = 0; r < 16; ++r) {
                if (!((bal >> r) & 1ull)) continue;
                const int qq = wq0 + r;
                const float qd = bf2f(qkv[base + (size_t)qq * 1536 + lane]);
                float ls = 0.f, av = 0.f;
                #pragma unroll 1
                for (int s = 0; s < S_; ++s) {
                    float xp = qd * bf2f(qkv[base + 512 + (size_t)s * 1536 + lane]);
                    #pragma unroll
                    for (int m = 32; m; m >>= 1) xp += __shfl_xor(xp, m);
                    float p = __expf(fminf(xp, 60.f));
                    ls += p;
                    av += p * bf2f(qkv[base + 1024 + (size_t)s * 1536 + lane]);
                }
                o[((size_t)b * S_ + qq) * 512 + h * 64 + lane] = __float2bfloat16(av / ls);
            }
        }
    }
}

// ---------------------------------------------------------------------------
extern "C" void kernel_launch(void* const* d_in, const int* in_sizes, int n_in,
                              void* d_out, int out_size, void* d_ws, size_t ws_size,
                              hipStream_t stream)
{
    const int*   tok   = (const int*)  d_in[0];
    const float* emb   = (const float*)d_in[1];
    const float* wq    = (const float*)d_in[2];
    const float* wk    = (const float*)d_in[3];
    const float* wv    = (const float*)d_in[4];
    const float* wo    = (const float*)d_in[5];
    const float* ln1_s = (const float*)d_in[6];
    const float* ln1_b = (const float*)d_in[7];
    const float* ln2_s = (const float*)d_in[8];
    const float* ln2_b = (const float*)d_in[9];
    const float* w1    = (const float*)d_in[10];
    const float* b1    = (const float*)d_in[11];
    const float* w2    = (const float*)d_in[12];
    const float* b2    = (const float*)d_in[13];
    const float* lnf_s = (const float*)d_in[14];
    const float* lnf_b = (const float*)d_in[15];
    float* out = (float*)d_out;

    char* ws = (char*)d_ws;
    float*          x     = (float*)(ws + 0);                    //  8.39 MB f32
    __hip_bfloat16* ybf   = (__hip_bfloat16*)(ws + 8388608);     //  4.19 MB bf16
    __hip_bfloat16* qkvbf = (__hip_bfloat16*)(ws + 12582912);    // 12.58 MB bf16
    __hip_bfloat16* ob    = (__hip_bfloat16*)(ws + 37748736);    //  4.19 MB bf16
    __hip_bfloat16* hb    = (__hip_bfloat16*)(ws + 41943040);    // 16.78 MB bf16
    int*            pad   = (int*)(ws + 58720256);               // 16 KB
    __hip_bfloat16* wT    = (__hip_bfloat16*)(ws + 58736640);    // 37.75 MB

    const int NT = B_ * S_;   // 4096

    transpose_cast<<<dim3(3072, L_), 256, 0, stream>>>(wq, wk, wv, wo, w1, w2, wT);
    embed_kernel<<<NT, 256, 0, stream>>>(tok, emb, x, pad);

    for (int l = 0; l < L_; ++l) {
        __hip_bfloat16* wTl = wT + (size_t)l * 3145728;
        ln_kernel<true><<<NT / 4, 256, 0, stream>>>(x, ln1_s + l * D_, ln1_b + l * D_, (void*)ybf);
        // fused QKV: [4096x512] x [512x1536] -> qkvbf [4096][1536] bf16
        gemm_1g<true, 0><<<768, 256, 0, stream>>>(ybf, wTl, nullptr, nullptr,
                                                  (void*)qkvbf, 512, 1536, 24, 0);
        attn_mfma_kernel<<<dim3(16, 16), 512, 0, stream>>>((const u16*)qkvbf, pad, ob);
        gemm_bk64<false, 1><<<256, 512, 0, stream>>>(ob, wTl + 786432, nullptr, x,
                                                     (void*)x, 512, 512, 8, 0);
        ln_kernel<true><<<NT / 4, 256, 0, stream>>>(x, ln2_s + l * D_, ln2_b + l * D_, (void*)ybf);
        gemm_1g<true, 2><<<1024, 256, 0, stream>>>(ybf, wTl + 1048576, b1 + l * M_, nullptr,
                                                   (void*)hb, 512, 2048, 32, 1);
        gemm_bk64<false, 3><<<256, 512, 0, stream>>>(hb, wTl + 2097152, b2 + l * D_, x,
                                                     (void*)x, 2048, 512, 8, 0);
    }
    ln_kernel<false><<<NT / 4, 256, 0, stream>>>(x, lnf_s, lnf_b, (void*)out);
}

// Round 16
// 663.500 us; speedup vs baseline: 1.0431x; 1.0431x over previous
//
#include <hip/hip_runtime.h>
#include <hip/hip_bf16.h>
#include <math.h>

#define B_    2
#define S_    2048
#define D_    512
#define H_    8
#define DH_   64
#define M_    2048
#define L_    6

typedef float f4v __attribute__((ext_vector_type(4)));
typedef short s8v __attribute__((ext_vector_type(8)));
typedef unsigned short u16;
typedef unsigned short u16x4 __attribute__((ext_vector_type(4)));

// async global->LDS, 16B per lane; LDS dest is wave-uniform base + lane*16
#define GLOAD16(gp, lp) __builtin_amdgcn_global_load_lds( \
    (const __attribute__((address_space(1))) void*)(gp),  \
    (__attribute__((address_space(3))) void*)(lp), 16, 0, 0)

__device__ __forceinline__ unsigned pack2bf(float a, float b) {
    __hip_bfloat162 t;
    t.x = __float2bfloat16(a);
    t.y = __float2bfloat16(b);
    return *(unsigned*)&t;
}
__device__ __forceinline__ float bf2f(u16 u) {
    unsigned v = ((unsigned)u) << 16;
    return *(float*)&v;
}
__device__ __forceinline__ u16 f2bf(float f) {
    __hip_bfloat16 h = __float2bfloat16(f);
    return *(u16*)&h;
}

// ---------------------------------------------------------------------------
// Fused startup: blocks [0,18432) = weight transpose+cast (W[K][N] f32 ->
// Wt[N][K] bf16, 6 layers; bakes 0.125 into wq); blocks [18432,22528) =
// embedding + sinusoidal pos + padding mask. Embed hides under transpose.
// ---------------------------------------------------------------------------
__global__ __launch_bounds__(256) void startup_kernel(
    const int* __restrict__ tok, const float* __restrict__ emb,
    const float* __restrict__ wq, const float* __restrict__ wk,
    const float* __restrict__ wv, const float* __restrict__ wo,
    const float* __restrict__ w1, const float* __restrict__ w2,
    __hip_bfloat16* __restrict__ dst,
    float* __restrict__ x, int* __restrict__ pad)
{
    __shared__ float tile[32][33];
    const int bid = blockIdx.x;
    if (bid >= 18432) {              // ---- embed path ----
        int t = bid - 18432;
        int s = t & (S_ - 1);
        int d = threadIdx.x;
        int tk = tok[t];
        if (d == 0) pad[t] = (tk > 0) ? 1 : 0;
        const float sf = -9.210340371976184f / 255.0f;
        float dt  = expf((float)d * sf);
        float ang = (float)s * dt;
        x[(size_t)t * D_ + d]       = emb[(size_t)tk * D_ + d]       + sinf(ang);
        x[(size_t)t * D_ + d + 256] = emb[(size_t)tk * D_ + d + 256] + cosf(ang);
        return;
    }
    // ---- transpose path ----
    const int l = bid / 3072;
    const int bx = bid % 3072;
    const size_t lbase = (size_t)l * 3145728;
    const float* src; __hip_bfloat16* d; int K, N, kt, nt;
    float wscale = 1.0f;
    if (bx < 1024) {
        int m = bx >> 8, t = bx & 255;
        const float* s4 = (m == 0) ? wq : (m == 1) ? wk : (m == 2) ? wv : wo;
        if (m == 0) wscale = 0.125f;
        src = s4 + (size_t)l * 262144;
        d = dst + lbase + (size_t)m * 262144;
        K = 512; N = 512; kt = t >> 4; nt = t & 15;
    } else if (bx < 2048) {
        int t = bx - 1024;
        src = w1 + (size_t)l * 1048576;
        d = dst + lbase + 1048576;
        K = 512; N = 2048; kt = t >> 6; nt = t & 63;
    } else {
        int t = bx - 2048;
        src = w2 + (size_t)l * 1048576;
        d = dst + lbase + 2097152;
        K = 2048; N = 512; kt = t >> 4; nt = t & 15;
    }
    const int xx = threadIdx.x & 31, yy = threadIdx.x >> 5;
    const int kk0 = kt * 32, nn0 = nt * 32;
    #pragma unroll
    for (int p = 0; p < 4; ++p)
        tile[yy + p * 8][xx] = src[(size_t)(kk0 + yy + p * 8) * N + nn0 + xx];
    __syncthreads();
    #pragma unroll
    for (int p = 0; p < 4; ++p)
        d[(size_t)(nn0 + yy + p * 8) * K + kk0 + xx] =
            __float2bfloat16(tile[xx][yy + p * 8] * wscale);
}

// ---------------------------------------------------------------------------
// LayerNorm, wave-per-token: 256 threads = 4 waves = 4 tokens, grid NT/4.
// ---------------------------------------------------------------------------
template<bool OBF16>
__global__ __launch_bounds__(256) void ln_kernel(
    const float* __restrict__ xin, const float* __restrict__ sc,
    const float* __restrict__ bi, void* __restrict__ yout)
{
    const int wave = threadIdx.x >> 6, lane = threadIdx.x & 63;
    const int t = blockIdx.x * 4 + wave;
    const float* row = xin + (size_t)t * D_;
    f4v a = *(const f4v*)&row[lane * 4];
    f4v b = *(const f4v*)&row[256 + lane * 4];
    float ssum = a.x + a.y + a.z + a.w + b.x + b.y + b.z + b.w;
    float ssq  = a.x*a.x + a.y*a.y + a.z*a.z + a.w*a.w
               + b.x*b.x + b.y*b.y + b.z*b.z + b.w*b.w;
    #pragma unroll
    for (int m = 32; m; m >>= 1) {
        ssum += __shfl_xor(ssum, m);
        ssq  += __shfl_xor(ssq,  m);
    }
    float mu  = ssum * (1.0f / D_);
    float var = ssq * (1.0f / D_) - mu * mu;
    float r   = rsqrtf(var + 1e-6f);
    f4v sa = *(const f4v*)&sc[lane * 4];
    f4v sb = *(const f4v*)&sc[256 + lane * 4];
    f4v ba = *(const f4v*)&bi[lane * 4];
    f4v bb = *(const f4v*)&bi[256 + lane * 4];
    f4v oa, ob2;
    oa.x = (a.x - mu) * r * sa.x + ba.x;  oa.y = (a.y - mu) * r * sa.y + ba.y;
    oa.z = (a.z - mu) * r * sa.z + ba.z;  oa.w = (a.w - mu) * r * sa.w + ba.w;
    ob2.x = (b.x - mu) * r * sb.x + bb.x; ob2.y = (b.y - mu) * r * sb.y + bb.y;
    ob2.z = (b.z - mu) * r * sb.z + bb.z; ob2.w = (b.w - mu) * r * sb.w + bb.w;
    if (OBF16) {
        u16* y = (u16*)yout + (size_t)t * D_;
        u16x4 pa, pb;
        pa.x = f2bf(oa.x); pa.y = f2bf(oa.y); pa.z = f2bf(oa.z); pa.w = f2bf(oa.w);
        pb.x = f2bf(ob2.x); pb.y = f2bf(ob2.y); pb.z = f2bf(ob2.z); pb.w = f2bf(ob2.w);
        *(u16x4*)&y[lane * 4] = pa;
        *(u16x4*)&y[256 + lane * 4] = pb;
    } else {
        float* y = (float*)yout + (size_t)t * D_;
        *(f4v*)&y[lane * 4] = oa;
        *(f4v*)&y[256 + lane * 4] = ob2;
    }
}

// ---------------------------------------------------------------------------
// fast tanh-GELU
// ---------------------------------------------------------------------------
__device__ __forceinline__ float gelu_tanh(float xx) {
    float u = fminf(fmaxf(xx, -10.f), 10.f);
    float t = 0.7978845608028654f * (u + 0.044715f * u * u * u);
    float e = __expf(2.f * t);
    float th = 1.f - 2.f * __builtin_amdgcn_rcpf(e + 1.f);
    return 0.5f * xx * (1.f + th);
}

// ---------------------------------------------------------------------------
// Single-K-group GEMM, 256 threads (4 waves), 128x64 block tile, wave C-tile
// 64x32, BK=32, 3-buffer pipeline, counted vmcnt 6/3/0, two barriers/step.
// LDS 36KB -> 4 blocks/CU. For QKV (768) and MLP1 (1024). (round-13 proven)
// ---------------------------------------------------------------------------
template<bool OUT_BF16, int TAG>
__global__ __launch_bounds__(256) void gemm_1g(
    const __hip_bfloat16* __restrict__ A, const __hip_bfloat16* __restrict__ Wt,
    const float* __restrict__ bias, const float* __restrict__ resid,
    void* __restrict__ Cout, int K, int ldc, int ncol, int gelu)
{
    __shared__ __align__(16) char lds[36864];   // 3 bufs x 12KB

    const int nwg = gridDim.x;
    const int cpx = nwg >> 3;
    const int bid = blockIdx.x;
    const int pos = (bid & 7) * cpx + (bid >> 3);
    const int row0 = (pos / ncol) * 128;
    const int col0 = (pos % ncol) * 64;

    const int tid = threadIdx.x, lane = tid & 63, wg = tid >> 6;  // 4 waves
    const int wr = wg >> 1, wc = wg & 1;
    const int lq = lane & 15, g = lane >> 4;

    const int nt = K >> 5;
    const char* Ab = (const char*)A;
    const char* Bt = (const char*)Wt;
    const int ldsrow = lane >> 2;
    const int swzseg = (lane & 3) ^ ((lane >> 3) & 3);
    const int slot8  = (g ^ ((lq >> 1) & 3)) * 8;

    f4v acc[4][2] = {};

    auto STAGE = [&](int c, int t) {
        const int k0 = t * 32;
        char* dst = lds + c * 12288;
        #pragma unroll
        for (int i2 = 0; i2 < 2; ++i2) {
            int seg = wg * 2 + i2;
            const char* gp = Ab + ((size_t)(row0 + seg * 16 + ldsrow) * K + k0) * 2 + swzseg * 16;
            GLOAD16(gp, dst + seg * 1024);
        }
        {
            const char* gp = Bt + ((size_t)(col0 + wg * 16 + ldsrow) * K + k0) * 2 + swzseg * 16;
            GLOAD16(gp, dst + 8192 + wg * 1024);
        }
    };

    STAGE(0, 0);
    STAGE(1, 1);
    STAGE(2, 2);

    for (int t = 0; t < nt; ++t) {
        if (t < nt - 2)      asm volatile("s_waitcnt vmcnt(6)" ::: "memory");
        else if (t < nt - 1) asm volatile("s_waitcnt vmcnt(3)" ::: "memory");
        else                 asm volatile("s_waitcnt vmcnt(0)" ::: "memory");
        __builtin_amdgcn_s_barrier();
        __builtin_amdgcn_sched_barrier(0);

        const unsigned short* Al = (const unsigned short*)(lds + (t % 3) * 12288);
        const unsigned short* Bl = Al + 4096;
        s8v af[4], bfv[2];
        #pragma unroll
        for (int mi = 0; mi < 4; ++mi)
            af[mi] = *(const s8v*)&Al[(wr * 64 + mi * 16 + lq) * 32 + slot8];
        #pragma unroll
        for (int ni = 0; ni < 2; ++ni)
            bfv[ni] = *(const s8v*)&Bl[(wc * 32 + ni * 16 + lq) * 32 + slot8];

        __builtin_amdgcn_s_setprio(1);
        #pragma unroll
        for (int mi = 0; mi < 4; ++mi)
            #pragma unroll
            for (int ni = 0; ni < 2; ++ni)
                acc[mi][ni] = __builtin_amdgcn_mfma_f32_16x16x32_bf16(af[mi], bfv[ni], acc[mi][ni], 0, 0, 0);
        __builtin_amdgcn_s_setprio(0);

        asm volatile("s_waitcnt lgkmcnt(0)" ::: "memory");
        __builtin_amdgcn_s_barrier();
        __builtin_amdgcn_sched_barrier(0);
        if (t + 3 < nt) STAGE(t % 3, t + 3);
    }

    #pragma unroll
    for (int mi = 0; mi < 4; ++mi) {
        #pragma unroll
        for (int ni = 0; ni < 2; ++ni) {
            #pragma unroll
            for (int jj = 0; jj < 4; ++jj) {
                int rrow = row0 + wr * 64 + mi * 16 + g * 4 + jj;
                int ccol = col0 + wc * 32 + ni * 16 + lq;
                float vv = acc[mi][ni][jj];
                if (bias)  vv += bias[ccol];
                if (gelu)  vv = gelu_tanh(vv);
                if (resid) vv += resid[(size_t)rrow * ldc + ccol];
                if (OUT_BF16)
                    ((__hip_bfloat16*)Cout)[(size_t)rrow * ldc + ccol] = __float2bfloat16(vv);
                else
                    ((float*)Cout)[(size_t)rrow * ldc + ccol] = vv;
            }
        }
    }
}

// ---------------------------------------------------------------------------
// Split-K2 GEMM, BK=64 per step — for the grid-256 (1 block/CU) GEMMs
// (o-proj, MLP2). (round-10 proven)
// ---------------------------------------------------------------------------
template<bool OUT_BF16, int TAG>
__global__ __launch_bounds__(512) void gemm_bk64(
    const __hip_bfloat16* __restrict__ A, const __hip_bfloat16* __restrict__ Wt,
    const float* __restrict__ bias, const float* __restrict__ resid,
    void* __restrict__ Cout, int K, int ldc, int ncol, int gelu)
{
    __shared__ __align__(16) char lds[147456];

    const int nwg = gridDim.x;
    const int cpx = nwg >> 3;
    const int bid = blockIdx.x;
    const int pos = (bid & 7) * cpx + (bid >> 3);
    const int row0 = (pos / ncol) * 128;
    const int col0 = (pos % ncol) * 64;

    const int tid = threadIdx.x, lane = tid & 63, w = tid >> 6;
    const int kg = w >> 2, wg = w & 3;
    const int wr = wg >> 1, wc = wg & 1;
    const int lq = lane & 15, g = lane >> 4;

    const int Kpart = K >> 1;
    const int nt = Kpart >> 6;
    const char* Ab = (const char*)A;
    const char* Bt = (const char*)Wt;
    const int srow8  = lane >> 3;
    const int schunk = lane & 7;
    const int gchunk = schunk ^ srow8;

    f4v acc[4][2] = {};

    auto STAGE = [&](int c, int t) {
        const int k0 = kg * Kpart + t * 64;
        char* dst = lds + (kg * 3 + c) * 24576;
        #pragma unroll
        for (int i2 = 0; i2 < 4; ++i2) {
            int seg = wg * 4 + i2;
            const char* gp = Ab + ((size_t)(row0 + seg * 8 + srow8) * K + k0) * 2 + gchunk * 16;
            GLOAD16(gp, dst + seg * 1024);
        }
        #pragma unroll
        for (int i2 = 0; i2 < 2; ++i2) {
            int seg = wg * 2 + i2;
            const char* gp = Bt + ((size_t)(col0 + seg * 8 + srow8) * K + k0) * 2 + gchunk * 16;
            GLOAD16(gp, dst + 16384 + seg * 1024);
        }
    };

    STAGE(0, 0);
    STAGE(1, 1);
    STAGE(2, 2);

    for (int t = 0; t < nt; ++t) {
        if (t < nt - 2)      asm volatile("s_waitcnt vmcnt(12)" ::: "memory");
        else if (t < nt - 1) asm volatile("s_waitcnt vmcnt(6)" ::: "memory");
        else                 asm volatile("s_waitcnt vmcnt(0)" ::: "memory");
        __builtin_amdgcn_s_barrier();
        __builtin_amdgcn_sched_barrier(0);

        const unsigned short* Al = (const unsigned short*)(lds + (kg * 3 + t % 3) * 24576);
        const unsigned short* Bl = Al + 8192;
        s8v af[4][2], bfv[2][2];
        #pragma unroll
        for (int ks = 0; ks < 2; ++ks) {
            #pragma unroll
            for (int mi = 0; mi < 4; ++mi) {
                const int r = wr * 64 + mi * 16 + lq;
                af[mi][ks] = *(const s8v*)&Al[r * 64 + (((ks * 4 + g) ^ (r & 7)) * 8)];
            }
            #pragma unroll
            for (int ni = 0; ni < 2; ++ni) {
                const int r = wc * 32 + ni * 16 + lq;
                bfv[ni][ks] = *(const s8v*)&Bl[r * 64 + (((ks * 4 + g) ^ (r & 7)) * 8)];
            }
        }

        __builtin_amdgcn_s_setprio(1);
        #pragma unroll
        for (int ks = 0; ks < 2; ++ks)
            #pragma unroll
            for (int mi = 0; mi < 4; ++mi)
                #pragma unroll
                for (int ni = 0; ni < 2; ++ni)
                    acc[mi][ni] = __builtin_amdgcn_mfma_f32_16x16x32_bf16(af[mi][ks], bfv[ni][ks], acc[mi][ni], 0, 0, 0);
        __builtin_amdgcn_s_setprio(0);

        asm volatile("s_waitcnt lgkmcnt(0)" ::: "memory");
        __builtin_amdgcn_s_barrier();
        __builtin_amdgcn_sched_barrier(0);
        if (t + 3 < nt) STAGE(t % 3, t + 3);
    }

    float* scr = (float*)lds;
    if (kg == 1) {
        #pragma unroll
        for (int mi = 0; mi < 4; ++mi)
            #pragma unroll
            for (int ni = 0; ni < 2; ++ni)
                *(f4v*)&scr[(((mi * 2 + ni) * 4 + wg) * 64 + lane) * 4] = acc[mi][ni];
    }
    __syncthreads();
    if (kg == 1) return;

    #pragma unroll
    for (int mi = 0; mi < 4; ++mi)
        #pragma unroll
        for (int ni = 0; ni < 2; ++ni)
            acc[mi][ni] += *(const f4v*)&scr[(((mi * 2 + ni) * 4 + wg) * 64 + lane) * 4];

    #pragma unroll
    for (int mi = 0; mi < 4; ++mi) {
        #pragma unroll
        for (int ni = 0; ni < 2; ++ni) {
            #pragma unroll
            for (int jj = 0; jj < 4; ++jj) {
                int rrow = row0 + wr * 64 + mi * 16 + g * 4 + jj;
                int ccol = col0 + wc * 32 + ni * 16 + lq;
                float vv = acc[mi][ni][jj];
                if (bias)  vv += bias[ccol];
                if (gelu)  vv = gelu_tanh(vv);
                if (resid) vv += resid[(size_t)rrow * ldc + ccol];
                if (OUT_BF16)
                    ((__hip_bfloat16*)Cout)[(size_t)rrow * ldc + ccol] = __float2bfloat16(vv);
                else
                    ((float*)Cout)[(size_t)rrow * ldc + ccol] = vv;
            }
        }
    }
}

// ---------------------------------------------------------------------------
// MFMA sliding-window attention, Q-tile 128, 8 waves, 64-key double-buffered
// chunks; async-stage split (T14). All qkv data bf16. (round-13 best)
// ---------------------------------------------------------------------------
__global__ __launch_bounds__(512) void attn_mfma_kernel(
    const u16* __restrict__ qkv, const int* __restrict__ pad,
    __hip_bfloat16* __restrict__ o)
{
    __shared__ __align__(16) unsigned short Klds[2][64 * 64];
    __shared__ __align__(16) unsigned short Vt[2][64 * 64];
    __shared__ float padfa[640];

    const int qt = blockIdx.x, bh = blockIdx.y;
    const int h = bh & 7, b = bh >> 3;
    const int q0 = qt * 128;
    const int tid = threadIdx.x, w = tid >> 6, lane = tid & 63;
    const int lq = lane & 15, g = lane >> 4;
    const int wq0 = q0 + w * 16;
    const size_t base = (size_t)b * S_ * 1536 + h * 64;

    for (int j = tid; j < 640; j += 512) {
        int krow = q0 - 256 + j;
        padfa[j] = (krow >= 0 && krow < S_ && pad[b * S_ + krow] != 0) ? 1.f : 0.f;
    }

    s8v qf[2];
    {
        const u16* qr = qkv + base + (size_t)(wq0 + lq) * 1536;
        #pragma unroll
        for (int ks = 0; ks < 2; ++ks)
            qf[ks] = *(const s8v*)&qr[ks * 32 + g * 8];
    }

    float lsum = 0.f;
    f4v oacc[4] = {};
    const int oblane = 256 + 4 * g - wq0 - lq;

    const int ki = tid >> 3, kss = tid & 7;
    const int vd = tid & 63, vkb = tid >> 6;
    s8v kreg;
    u16 vreg0, vreg1, vreg2, vreg3, vreg4, vreg5, vreg6, vreg7;

    auto LOAD_REGS = [&](int c) {
        const int kc = q0 - 256 + c * 64;
        {
            int krow = kc + ki;
            int kcl = krow < 0 ? 0 : (krow >= S_ ? S_ - 1 : krow);
            kreg = *(const s8v*)&qkv[base + 512 + (size_t)kcl * 1536 + kss * 8];
        }
        {
            int kr0 = kc + vkb * 8;
            const u16* vp = qkv + base + 1024 + vd;
            int c0 = kr0+0 < 0 ? 0 : (kr0+0 >= S_ ? S_-1 : kr0+0);
            int c1 = kr0+1 < 0 ? 0 : (kr0+1 >= S_ ? S_-1 : kr0+1);
            int c2 = kr0+2 < 0 ? 0 : (kr0+2 >= S_ ? S_-1 : kr0+2);
            int c3 = kr0+3 < 0 ? 0 : (kr0+3 >= S_ ? S_-1 : kr0+3);
            int c4 = kr0+4 < 0 ? 0 : (kr0+4 >= S_ ? S_-1 : kr0+4);
            int c5 = kr0+5 < 0 ? 0 : (kr0+5 >= S_ ? S_-1 : kr0+5);
            int c6 = kr0+6 < 0 ? 0 : (kr0+6 >= S_ ? S_-1 : kr0+6);
            int c7 = kr0+7 < 0 ? 0 : (kr0+7 >= S_ ? S_-1 : kr0+7);
            vreg0 = vp[(size_t)c0 * 1536]; vreg1 = vp[(size_t)c1 * 1536];
            vreg2 = vp[(size_t)c2 * 1536]; vreg3 = vp[(size_t)c3 * 1536];
            vreg4 = vp[(size_t)c4 * 1536]; vreg5 = vp[(size_t)c5 * 1536];
            vreg6 = vp[(size_t)c6 * 1536]; vreg7 = vp[(size_t)c7 * 1536];
        }
    };
    auto WRITE_LDS = [&](int buf) {
        *(s8v*)&Klds[buf][ki * 64 + ((kss ^ (ki & 7)) * 8)] = kreg;
        union { s8v s; u16 u[8]; } vv;
        vv.u[0] = vreg0; vv.u[1] = vreg1; vv.u[2] = vreg2; vv.u[3] = vreg3;
        vv.u[4] = vreg4; vv.u[5] = vreg5; vv.u[6] = vreg6; vv.u[7] = vreg7;
        *(s8v*)&Vt[buf][vd * 64 + ((vkb ^ (vd & 7)) * 8)] = vv.s;
    };

    LOAD_REGS(0);
    WRITE_LDS(0);
    LOAD_REGS(1);

    #pragma unroll 1
    for (int c = 0; c < 10; ++c) {
        asm volatile("s_waitcnt lgkmcnt(0)" ::: "memory");
        __builtin_amdgcn_s_barrier();
        __builtin_amdgcn_sched_barrier(0);
        const int kc = q0 - 256 + c * 64;
        const int buf = c & 1;

        #pragma unroll
        for (int sub = 0; sub < 2; ++sub) {
            const int kc2 = kc + sub * 32;
            if (kc2 + 31 < wq0 - 256 || kc2 > wq0 + 271) continue;

            f4v st[2] = {};
            __builtin_amdgcn_s_setprio(1);
            #pragma unroll
            for (int tt = 0; tt < 2; ++tt) {
                #pragma unroll
                for (int ks = 0; ks < 2; ++ks) {
                    const int row = sub * 32 + tt * 16 + lq;
                    const s8v af = *(const s8v*)&Klds[buf][row * 64 + (((ks * 4 + g) ^ (row & 7)) * 8)];
                    st[tt] = __builtin_amdgcn_mfma_f32_16x16x32_bf16(af, qf[ks], st[tt], 0, 0, 0);
                }
            }
            __builtin_amdgcn_s_setprio(0);

            float psum = 0.f;
            unsigned wpk[2][2];
            #pragma unroll
            for (int tt = 0; tt < 2; ++tt) {
                float pr[4];
                #pragma unroll
                for (int r = 0; r < 4; ++r) {
                    const int off = kc2 + 16 * tt + r + oblane;
                    float e = __expf(fminf(st[tt][r], 60.f)) *
                              padfa[c * 64 + sub * 32 + 16 * tt + 4 * g + r];
                    pr[r] = ((unsigned)off <= 512u) ? e : 0.f;
                    psum += pr[r];
                }
                wpk[tt][0] = pack2bf(pr[0], pr[1]);
                wpk[tt][1] = pack2bf(pr[2], pr[3]);
            }
            psum += __shfl_xor(psum, 16);
            psum += __shfl_xor(psum, 32);
            lsum += psum;

            const int srcA = (((2 * g) & 3) * 16 + lq) << 2;
            const int srcB = (((2 * g + 1) & 3) * 16 + lq) << 2;
            const bool hi = (g >= 2);
            union { s8v s; int u[4]; } pa;
            {
                int a0 = __builtin_amdgcn_ds_bpermute(srcA, (int)wpk[0][0]);
                int a1 = __builtin_amdgcn_ds_bpermute(srcA, (int)wpk[1][0]);
                pa.u[0] = hi ? a1 : a0;
                int b0 = __builtin_amdgcn_ds_bpermute(srcA, (int)wpk[0][1]);
                int b1 = __builtin_amdgcn_ds_bpermute(srcA, (int)wpk[1][1]);
                pa.u[1] = hi ? b1 : b0;
                int c0 = __builtin_amdgcn_ds_bpermute(srcB, (int)wpk[0][0]);
                int c1 = __builtin_amdgcn_ds_bpermute(srcB, (int)wpk[1][0]);
                pa.u[2] = hi ? c1 : c0;
                int d0 = __builtin_amdgcn_ds_bpermute(srcB, (int)wpk[0][1]);
                int d1 = __builtin_amdgcn_ds_bpermute(srcB, (int)wpk[1][1]);
                pa.u[3] = hi ? d1 : d0;
            }

            __builtin_amdgcn_s_setprio(1);
            #pragma unroll
            for (int dt = 0; dt < 4; ++dt) {
                const int row = dt * 16 + lq;
                const s8v vf = *(const s8v*)&Vt[buf][row * 64 + (((sub * 4 + g) ^ (row & 7)) * 8)];
                oacc[dt] = __builtin_amdgcn_mfma_f32_16x16x32_bf16(pa.s, vf, oacc[dt], 0, 0, 0);
            }
            __builtin_amdgcn_s_setprio(0);
        }

        if (c + 1 < 10) WRITE_LDS((c + 1) & 1);
        if (c + 2 < 10) LOAD_REGS(c + 2);
    }

    float inv = 1.0f / lsum;
    #pragma unroll
    for (int r = 0; r < 4; ++r) {
        int iv = __builtin_amdgcn_ds_bpermute((4 * g + r) << 2, __float_as_int(inv));
        float invq = __int_as_float(iv);
        const int qq = wq0 + 4 * g + r;
        __hip_bfloat16* orow = o + ((size_t)b * S_ + qq) * 512 + h * 64;
        #pragma unroll
        for (int dt = 0; dt < 4; ++dt)
            orow[dt * 16 + lq] = __float2bfloat16(oacc[dt][r] * invq);
    }

    // rare path: pad[q]==0 -> plain softmax over ALL S keys (overwrites)
    {
        int padq = pad[b * S_ + wq0 + lq];
        unsigned long long bal = __ballot(g == 0 && padq == 0);
        if (bal) {
            #pragma unroll 1
            for (int r = 0; r < 16; ++r) {
                if (!((bal >> r) & 1ull)) continue;
                const int qq = wq0 + r;
                const float qd = bf2f(qkv[base + (size_t)qq * 1536 + lane]);
                float ls = 0.f, av = 0.f;
                #pragma unroll 1
                for (int s = 0; s < S_; ++s) {
                    float xp = qd * bf2f(qkv[base + 512 + (size_t)s * 1536 + lane]);
                    #pragma unroll
                    for (int m = 32; m; m >>= 1) xp += __shfl_xor(xp, m);
                    float p = __expf(fminf(xp, 60.f));
                    ls += p;
                    av += p * bf2f(qkv[base + 1024 + (size_t)s * 1536 + lane]);
                }
                o[((size_t)b * S_ + qq) * 512 + h * 64 + lane] = __float2bfloat16(av / ls);
            }
        }
    }
}

// ---------------------------------------------------------------------------
extern "C" void kernel_launch(void* const* d_in, const int* in_sizes, int n_in,
                              void* d_out, int out_size, void* d_ws, size_t ws_size,
                              hipStream_t stream)
{
    const int*   tok   = (const int*)  d_in[0];
    const float* emb   = (const float*)d_in[1];
    const float* wq    = (const float*)d_in[2];
    const float* wk    = (const float*)d_in[3];
    const float* wv    = (const float*)d_in[4];
    const float* wo    = (const float*)d_in[5];
    const float* ln1_s = (const float*)d_in[6];
    const float* ln1_b = (const float*)d_in[7];
    const float* ln2_s = (const float*)d_in[8];
    const float* ln2_b = (const float*)d_in[9];
    const float* w1    = (const float*)d_in[10];
    const float* b1    = (const float*)d_in[11];
    const float* w2    = (const float*)d_in[12];
    const float* b2    = (const float*)d_in[13];
    const float* lnf_s = (const float*)d_in[14];
    const float* lnf_b = (const float*)d_in[15];
    float* out = (float*)d_out;

    char* ws = (char*)d_ws;
    float*          x     = (float*)(ws + 0);                    //  8.39 MB f32
    __hip_bfloat16* ybf   = (__hip_bfloat16*)(ws + 8388608);     //  4.19 MB bf16
    __hip_bfloat16* qkvbf = (__hip_bfloat16*)(ws + 12582912);    // 12.58 MB bf16
    __hip_bfloat16* ob    = (__hip_bfloat16*)(ws + 37748736);    //  4.19 MB bf16
    __hip_bfloat16* hb    = (__hip_bfloat16*)(ws + 41943040);    // 16.78 MB bf16
    int*            pad   = (int*)(ws + 58720256);               // 16 KB
    __hip_bfloat16* wT    = (__hip_bfloat16*)(ws + 58736640);    // 37.75 MB

    const int NT = B_ * S_;   // 4096

    startup_kernel<<<22528, 256, 0, stream>>>(tok, emb, wq, wk, wv, wo, w1, w2,
                                              wT, x, pad);

    for (int l = 0; l < L_; ++l) {
        __hip_bfloat16* wTl = wT + (size_t)l * 3145728;
        ln_kernel<true><<<NT / 4, 256, 0, stream>>>(x, ln1_s + l * D_, ln1_b + l * D_, (void*)ybf);
        // fused QKV: [4096x512] x [512x1536] -> qkvbf [4096][1536] bf16
        gemm_1g<true, 0><<<768, 256, 0, stream>>>(ybf, wTl, nullptr, nullptr,
                                                  (void*)qkvbf, 512, 1536, 24, 0);
        attn_mfma_kernel<<<dim3(16, 16), 512, 0, stream>>>((const u16*)qkvbf, pad, ob);
        gemm_bk64<false, 1><<<256, 512, 0, stream>>>(ob, wTl + 786432, nullptr, x,
                                                     (void*)x, 512, 512, 8, 0);
        ln_kernel<true><<<NT / 4, 256, 0, stream>>>(x, ln2_s + l * D_, ln2_b + l * D_, (void*)ybf);
        gemm_1g<true, 2><<<1024, 256, 0, stream>>>(ybf, wTl + 1048576, b1 + l * M_, nullptr,
                                                   (void*)hb, 512, 2048, 32, 1);
        gemm_bk64<false, 3><<<256, 512, 0, stream>>>(hb, wTl + 2097152, b2 + l * D_, x,
                                                     (void*)x, 2048, 512, 8, 0);
    }
    ln_kernel<false><<<NT / 4, 256, 0, stream>>>(x, lnf_s, lnf_b, (void*)out);
}

// Round 17
// 646.400 us; speedup vs baseline: 1.0707x; 1.0265x over previous
//
#include <hip/hip_runtime.h>
#include <hip/hip_bf16.h>
#include <math.h>

#define B_    2
#define S_    2048
#define D_    512
#define H_    8
#define DH_   64
#define M_    2048
#define L_    6

typedef float f4v __attribute__((ext_vector_type(4)));
typedef short s8v __attribute__((ext_vector_type(8)));
typedef unsigned short u16;
typedef unsigned short u16x4 __attribute__((ext_vector_type(4)));

// async global->LDS, 16B per lane; LDS dest is wave-uniform base + lane*16
#define GLOAD16(gp, lp) __builtin_amdgcn_global_load_lds( \
    (const __attribute__((address_space(1))) void*)(gp),  \
    (__attribute__((address_space(3))) void*)(lp), 16, 0, 0)

__device__ __forceinline__ unsigned pack2bf(float a, float b) {
    __hip_bfloat162 t;
    t.x = __float2bfloat16(a);
    t.y = __float2bfloat16(b);
    return *(unsigned*)&t;
}
__device__ __forceinline__ float bf2f(u16 u) {
    unsigned v = ((unsigned)u) << 16;
    return *(float*)&v;
}
__device__ __forceinline__ u16 f2bf(float f) {
    __hip_bfloat16 h = __float2bfloat16(f);
    return *(u16*)&h;
}

// ---------------------------------------------------------------------------
// Fused startup: blocks [0,18432) = weight transpose+cast; blocks
// [18432,22528) = embedding (bf16 x) + padding mask.
// ---------------------------------------------------------------------------
__global__ __launch_bounds__(256) void startup_kernel(
    const int* __restrict__ tok, const float* __restrict__ emb,
    const float* __restrict__ wq, const float* __restrict__ wk,
    const float* __restrict__ wv, const float* __restrict__ wo,
    const float* __restrict__ w1, const float* __restrict__ w2,
    __hip_bfloat16* __restrict__ dst,
    u16* __restrict__ x, int* __restrict__ pad)
{
    __shared__ float tile[32][33];
    const int bid = blockIdx.x;
    if (bid >= 18432) {              // ---- embed path (bf16 residual) ----
        int t = bid - 18432;
        int s = t & (S_ - 1);
        int d = threadIdx.x;
        int tk = tok[t];
        if (d == 0) pad[t] = (tk > 0) ? 1 : 0;
        const float sf = -9.210340371976184f / 255.0f;
        float dt  = expf((float)d * sf);
        float ang = (float)s * dt;
        x[(size_t)t * D_ + d]       = f2bf(emb[(size_t)tk * D_ + d]       + sinf(ang));
        x[(size_t)t * D_ + d + 256] = f2bf(emb[(size_t)tk * D_ + d + 256] + cosf(ang));
        return;
    }
    // ---- transpose path ----
    const int l = bid / 3072;
    const int bx = bid % 3072;
    const size_t lbase = (size_t)l * 3145728;
    const float* src; __hip_bfloat16* d; int K, N, kt, nt;
    float wscale = 1.0f;
    if (bx < 1024) {
        int m = bx >> 8, t = bx & 255;
        const float* s4 = (m == 0) ? wq : (m == 1) ? wk : (m == 2) ? wv : wo;
        if (m == 0) wscale = 0.125f;
        src = s4 + (size_t)l * 262144;
        d = dst + lbase + (size_t)m * 262144;
        K = 512; N = 512; kt = t >> 4; nt = t & 15;
    } else if (bx < 2048) {
        int t = bx - 1024;
        src = w1 + (size_t)l * 1048576;
        d = dst + lbase + 1048576;
        K = 512; N = 2048; kt = t >> 6; nt = t & 63;
    } else {
        int t = bx - 2048;
        src = w2 + (size_t)l * 1048576;
        d = dst + lbase + 2097152;
        K = 2048; N = 512; kt = t >> 4; nt = t & 15;
    }
    const int xx = threadIdx.x & 31, yy = threadIdx.x >> 5;
    const int kk0 = kt * 32, nn0 = nt * 32;
    #pragma unroll
    for (int p = 0; p < 4; ++p)
        tile[yy + p * 8][xx] = src[(size_t)(kk0 + yy + p * 8) * N + nn0 + xx];
    __syncthreads();
    #pragma unroll
    for (int p = 0; p < 4; ++p)
        d[(size_t)(nn0 + yy + p * 8) * K + kk0 + xx] =
            __float2bfloat16(tile[xx][yy + p * 8] * wscale);
}

// ---------------------------------------------------------------------------
// LayerNorm over bf16 residual x, wave-per-token: 4 waves = 4 tokens.
// Lane loads 8 bf16 (one 16B load); OBF16 -> bf16 out, else f32 out.
// ---------------------------------------------------------------------------
template<bool OBF16>
__global__ __launch_bounds__(256) void ln_kernel(
    const u16* __restrict__ xin, const float* __restrict__ sc,
    const float* __restrict__ bi, void* __restrict__ yout)
{
    const int wave = threadIdx.x >> 6, lane = threadIdx.x & 63;
    const int t = blockIdx.x * 4 + wave;
    union { s8v s; u16 u[8]; } vv;
    vv.s = *(const s8v*)&xin[(size_t)t * D_ + lane * 8];
    float v[8];
    #pragma unroll
    for (int j = 0; j < 8; ++j) v[j] = bf2f(vv.u[j]);
    float ssum = 0.f, ssq = 0.f;
    #pragma unroll
    for (int j = 0; j < 8; ++j) { ssum += v[j]; ssq += v[j] * v[j]; }
    #pragma unroll
    for (int m = 32; m; m >>= 1) {
        ssum += __shfl_xor(ssum, m);
        ssq  += __shfl_xor(ssq,  m);
    }
    float mu  = ssum * (1.0f / D_);
    float var = ssq * (1.0f / D_) - mu * mu;
    float r   = rsqrtf(var + 1e-6f);
    f4v sa = *(const f4v*)&sc[lane * 8];
    f4v sb = *(const f4v*)&sc[lane * 8 + 4];
    f4v ba = *(const f4v*)&bi[lane * 8];
    f4v bb = *(const f4v*)&bi[lane * 8 + 4];
    float ov[8];
    ov[0] = (v[0] - mu) * r * sa.x + ba.x;  ov[1] = (v[1] - mu) * r * sa.y + ba.y;
    ov[2] = (v[2] - mu) * r * sa.z + ba.z;  ov[3] = (v[3] - mu) * r * sa.w + ba.w;
    ov[4] = (v[4] - mu) * r * sb.x + bb.x;  ov[5] = (v[5] - mu) * r * sb.y + bb.y;
    ov[6] = (v[6] - mu) * r * sb.z + bb.z;  ov[7] = (v[7] - mu) * r * sb.w + bb.w;
    if (OBF16) {
        union { s8v s; u16 u[8]; } pv;
        #pragma unroll
        for (int j = 0; j < 8; ++j) pv.u[j] = f2bf(ov[j]);
        *(s8v*)&((u16*)yout)[(size_t)t * D_ + lane * 8] = pv.s;
    } else {
        float* y = (float*)yout + (size_t)t * D_ + lane * 8;
        f4v oa, ob2;
        oa.x = ov[0]; oa.y = ov[1]; oa.z = ov[2]; oa.w = ov[3];
        ob2.x = ov[4]; ob2.y = ov[5]; ob2.z = ov[6]; ob2.w = ov[7];
        *(f4v*)&y[0] = oa;
        *(f4v*)&y[4] = ob2;
    }
}

// ---------------------------------------------------------------------------
// fast tanh-GELU
// ---------------------------------------------------------------------------
__device__ __forceinline__ float gelu_tanh(float xx) {
    float u = fminf(fmaxf(xx, -10.f), 10.f);
    float t = 0.7978845608028654f * (u + 0.044715f * u * u * u);
    float e = __expf(2.f * t);
    float th = 1.f - 2.f * __builtin_amdgcn_rcpf(e + 1.f);
    return 0.5f * xx * (1.f + th);
}

// ---------------------------------------------------------------------------
// Single-K-group GEMM, 256 threads (4 waves), 128x64 block tile, wave C-tile
// 64x32, BK=32, 3-buffer pipeline, counted vmcnt 6/3/0, two barriers/step.
// LDS 36KB -> 4 blocks/CU. For QKV (768) and MLP1 (1024). Output bf16.
// ---------------------------------------------------------------------------
template<int TAG>
__global__ __launch_bounds__(256) void gemm_1g(
    const __hip_bfloat16* __restrict__ A, const __hip_bfloat16* __restrict__ Wt,
    const float* __restrict__ bias, void* __restrict__ Cout,
    int K, int ldc, int ncol, int gelu)
{
    __shared__ __align__(16) char lds[36864];   // 3 bufs x 12KB

    const int nwg = gridDim.x;
    const int cpx = nwg >> 3;
    const int bid = blockIdx.x;
    const int pos = (bid & 7) * cpx + (bid >> 3);
    const int row0 = (pos / ncol) * 128;
    const int col0 = (pos % ncol) * 64;

    const int tid = threadIdx.x, lane = tid & 63, wg = tid >> 6;  // 4 waves
    const int wr = wg >> 1, wc = wg & 1;
    const int lq = lane & 15, g = lane >> 4;

    const int nt = K >> 5;
    const char* Ab = (const char*)A;
    const char* Bt = (const char*)Wt;
    const int ldsrow = lane >> 2;
    const int swzseg = (lane & 3) ^ ((lane >> 3) & 3);
    const int slot8  = (g ^ ((lq >> 1) & 3)) * 8;

    f4v acc[4][2] = {};

    auto STAGE = [&](int c, int t) {
        const int k0 = t * 32;
        char* dst = lds + c * 12288;
        #pragma unroll
        for (int i2 = 0; i2 < 2; ++i2) {
            int seg = wg * 2 + i2;
            const char* gp = Ab + ((size_t)(row0 + seg * 16 + ldsrow) * K + k0) * 2 + swzseg * 16;
            GLOAD16(gp, dst + seg * 1024);
        }
        {
            const char* gp = Bt + ((size_t)(col0 + wg * 16 + ldsrow) * K + k0) * 2 + swzseg * 16;
            GLOAD16(gp, dst + 8192 + wg * 1024);
        }
    };

    STAGE(0, 0);
    STAGE(1, 1);
    STAGE(2, 2);

    for (int t = 0; t < nt; ++t) {
        if (t < nt - 2)      asm volatile("s_waitcnt vmcnt(6)" ::: "memory");
        else if (t < nt - 1) asm volatile("s_waitcnt vmcnt(3)" ::: "memory");
        else                 asm volatile("s_waitcnt vmcnt(0)" ::: "memory");
        __builtin_amdgcn_s_barrier();
        __builtin_amdgcn_sched_barrier(0);

        const unsigned short* Al = (const unsigned short*)(lds + (t % 3) * 12288);
        const unsigned short* Bl = Al + 4096;
        s8v af[4], bfv[2];
        #pragma unroll
        for (int mi = 0; mi < 4; ++mi)
            af[mi] = *(const s8v*)&Al[(wr * 64 + mi * 16 + lq) * 32 + slot8];
        #pragma unroll
        for (int ni = 0; ni < 2; ++ni)
            bfv[ni] = *(const s8v*)&Bl[(wc * 32 + ni * 16 + lq) * 32 + slot8];

        __builtin_amdgcn_s_setprio(1);
        #pragma unroll
        for (int mi = 0; mi < 4; ++mi)
            #pragma unroll
            for (int ni = 0; ni < 2; ++ni)
                acc[mi][ni] = __builtin_amdgcn_mfma_f32_16x16x32_bf16(af[mi], bfv[ni], acc[mi][ni], 0, 0, 0);
        __builtin_amdgcn_s_setprio(0);

        asm volatile("s_waitcnt lgkmcnt(0)" ::: "memory");
        __builtin_amdgcn_s_barrier();
        __builtin_amdgcn_sched_barrier(0);
        if (t + 3 < nt) STAGE(t % 3, t + 3);
    }

    #pragma unroll
    for (int mi = 0; mi < 4; ++mi) {
        #pragma unroll
        for (int ni = 0; ni < 2; ++ni) {
            #pragma unroll
            for (int jj = 0; jj < 4; ++jj) {
                int rrow = row0 + wr * 64 + mi * 16 + g * 4 + jj;
                int ccol = col0 + wc * 32 + ni * 16 + lq;
                float vv = acc[mi][ni][jj];
                if (bias)  vv += bias[ccol];
                if (gelu)  vv = gelu_tanh(vv);
                ((u16*)Cout)[(size_t)rrow * ldc + ccol] = f2bf(vv);
            }
        }
    }
}

// ---------------------------------------------------------------------------
// Split-K2 GEMM, BK=64 per step — for the grid-256 (1 block/CU) GEMMs
// (o-proj, MLP2). Residual and output are bf16 (residual stream).
// ---------------------------------------------------------------------------
template<int TAG>
__global__ __launch_bounds__(512) void gemm_bk64(
    const __hip_bfloat16* __restrict__ A, const __hip_bfloat16* __restrict__ Wt,
    const float* __restrict__ bias, const u16* __restrict__ resid,
    u16* __restrict__ Cout, int K, int ldc, int ncol, int gelu)
{
    __shared__ __align__(16) char lds[147456];

    const int nwg = gridDim.x;
    const int cpx = nwg >> 3;
    const int bid = blockIdx.x;
    const int pos = (bid & 7) * cpx + (bid >> 3);
    const int row0 = (pos / ncol) * 128;
    const int col0 = (pos % ncol) * 64;

    const int tid = threadIdx.x, lane = tid & 63, w = tid >> 6;
    const int kg = w >> 2, wg = w & 3;
    const int wr = wg >> 1, wc = wg & 1;
    const int lq = lane & 15, g = lane >> 4;

    const int Kpart = K >> 1;
    const int nt = Kpart >> 6;
    const char* Ab = (const char*)A;
    const char* Bt = (const char*)Wt;
    const int srow8  = lane >> 3;
    const int schunk = lane & 7;
    const int gchunk = schunk ^ srow8;

    f4v acc[4][2] = {};

    auto STAGE = [&](int c, int t) {
        const int k0 = kg * Kpart + t * 64;
        char* dst = lds + (kg * 3 + c) * 24576;
        #pragma unroll
        for (int i2 = 0; i2 < 4; ++i2) {
            int seg = wg * 4 + i2;
            const char* gp = Ab + ((size_t)(row0 + seg * 8 + srow8) * K + k0) * 2 + gchunk * 16;
            GLOAD16(gp, dst + seg * 1024);
        }
        #pragma unroll
        for (int i2 = 0; i2 < 2; ++i2) {
            int seg = wg * 2 + i2;
            const char* gp = Bt + ((size_t)(col0 + seg * 8 + srow8) * K + k0) * 2 + gchunk * 16;
            GLOAD16(gp, dst + 16384 + seg * 1024);
        }
    };

    STAGE(0, 0);
    STAGE(1, 1);
    STAGE(2, 2);

    for (int t = 0; t < nt; ++t) {
        if (t < nt - 2)      asm volatile("s_waitcnt vmcnt(12)" ::: "memory");
        else if (t < nt - 1) asm volatile("s_waitcnt vmcnt(6)" ::: "memory");
        else                 asm volatile("s_waitcnt vmcnt(0)" ::: "memory");
        __builtin_amdgcn_s_barrier();
        __builtin_amdgcn_sched_barrier(0);

        const unsigned short* Al = (const unsigned short*)(lds + (kg * 3 + t % 3) * 24576);
        const unsigned short* Bl = Al + 8192;
        s8v af[4][2], bfv[2][2];
        #pragma unroll
        for (int ks = 0; ks < 2; ++ks) {
            #pragma unroll
            for (int mi = 0; mi < 4; ++mi) {
                const int r = wr * 64 + mi * 16 + lq;
                af[mi][ks] = *(const s8v*)&Al[r * 64 + (((ks * 4 + g) ^ (r & 7)) * 8)];
            }
            #pragma unroll
            for (int ni = 0; ni < 2; ++ni) {
                const int r = wc * 32 + ni * 16 + lq;
                bfv[ni][ks] = *(const s8v*)&Bl[r * 64 + (((ks * 4 + g) ^ (r & 7)) * 8)];
            }
        }

        __builtin_amdgcn_s_setprio(1);
        #pragma unroll
        for (int ks = 0; ks < 2; ++ks)
            #pragma unroll
            for (int mi = 0; mi < 4; ++mi)
                #pragma unroll
                for (int ni = 0; ni < 2; ++ni)
                    acc[mi][ni] = __builtin_amdgcn_mfma_f32_16x16x32_bf16(af[mi][ks], bfv[ni][ks], acc[mi][ni], 0, 0, 0);
        __builtin_amdgcn_s_setprio(0);

        asm volatile("s_waitcnt lgkmcnt(0)" ::: "memory");
        __builtin_amdgcn_s_barrier();
        __builtin_amdgcn_sched_barrier(0);
        if (t + 3 < nt) STAGE(t % 3, t + 3);
    }

    float* scr = (float*)lds;
    if (kg == 1) {
        #pragma unroll
        for (int mi = 0; mi < 4; ++mi)
            #pragma unroll
            for (int ni = 0; ni < 2; ++ni)
                *(f4v*)&scr[(((mi * 2 + ni) * 4 + wg) * 64 + lane) * 4] = acc[mi][ni];
    }
    __syncthreads();
    if (kg == 1) return;

    #pragma unroll
    for (int mi = 0; mi < 4; ++mi)
        #pragma unroll
        for (int ni = 0; ni < 2; ++ni)
            acc[mi][ni] += *(const f4v*)&scr[(((mi * 2 + ni) * 4 + wg) * 64 + lane) * 4];

    #pragma unroll
    for (int mi = 0; mi < 4; ++mi) {
        #pragma unroll
        for (int ni = 0; ni < 2; ++ni) {
            #pragma unroll
            for (int jj = 0; jj < 4; ++jj) {
                int rrow = row0 + wr * 64 + mi * 16 + g * 4 + jj;
                int ccol = col0 + wc * 32 + ni * 16 + lq;
                float vv = acc[mi][ni][jj];
                if (bias)  vv += bias[ccol];
                if (gelu)  vv = gelu_tanh(vv);
                vv += bf2f(resid[(size_t)rrow * ldc + ccol]);
                Cout[(size_t)rrow * ldc + ccol] = f2bf(vv);
            }
        }
    }
}

// ---------------------------------------------------------------------------
// MFMA sliding-window attention, Q-tile 128, 8 waves, 64-key double-buffered
// chunks; async-stage split (T14). All qkv data bf16. (round-13 best)
// ---------------------------------------------------------------------------
__global__ __launch_bounds__(512) void attn_mfma_kernel(
    const u16* __restrict__ qkv, const int* __restrict__ pad,
    __hip_bfloat16* __restrict__ o)
{
    __shared__ __align__(16) unsigned short Klds[2][64 * 64];
    __shared__ __align__(16) unsigned short Vt[2][64 * 64];
    __shared__ float padfa[640];

    const int qt = blockIdx.x, bh = blockIdx.y;
    const int h = bh & 7, b = bh >> 3;
    const int q0 = qt * 128;
    const int tid = threadIdx.x, w = tid >> 6, lane = tid & 63;
    const int lq = lane & 15, g = lane >> 4;
    const int wq0 = q0 + w * 16;
    const size_t base = (size_t)b * S_ * 1536 + h * 64;

    for (int j = tid; j < 640; j += 512) {
        int krow = q0 - 256 + j;
        padfa[j] = (krow >= 0 && krow < S_ && pad[b * S_ + krow] != 0) ? 1.f : 0.f;
    }

    s8v qf[2];
    {
        const u16* qr = qkv + base + (size_t)(wq0 + lq) * 1536;
        #pragma unroll
        for (int ks = 0; ks < 2; ++ks)
            qf[ks] = *(const s8v*)&qr[ks * 32 + g * 8];
    }

    float lsum = 0.f;
    f4v oacc[4] = {};
    const int oblane = 256 + 4 * g - wq0 - lq;

    const int ki = tid >> 3, kss = tid & 7;
    const int vd = tid & 63, vkb = tid >> 6;
    s8v kreg;
    u16 vreg0, vreg1, vreg2, vreg3, vreg4, vreg5, vreg6, vreg7;

    auto LOAD_REGS = [&](int c) {
        const int kc = q0 - 256 + c * 64;
        {
            int krow = kc + ki;
            int kcl = krow < 0 ? 0 : (krow >= S_ ? S_ - 1 : krow);
            kreg = *(const s8v*)&qkv[base + 512 + (size_t)kcl * 1536 + kss * 8];
        }
        {
            int kr0 = kc + vkb * 8;
            const u16* vp = qkv + base + 1024 + vd;
            int c0 = kr0+0 < 0 ? 0 : (kr0+0 >= S_ ? S_-1 : kr0+0);
            int c1 = kr0+1 < 0 ? 0 : (kr0+1 >= S_ ? S_-1 : kr0+1);
            int c2 = kr0+2 < 0 ? 0 : (kr0+2 >= S_ ? S_-1 : kr0+2);
            int c3 = kr0+3 < 0 ? 0 : (kr0+3 >= S_ ? S_-1 : kr0+3);
            int c4 = kr0+4 < 0 ? 0 : (kr0+4 >= S_ ? S_-1 : kr0+4);
            int c5 = kr0+5 < 0 ? 0 : (kr0+5 >= S_ ? S_-1 : kr0+5);
            int c6 = kr0+6 < 0 ? 0 : (kr0+6 >= S_ ? S_-1 : kr0+6);
            int c7 = kr0+7 < 0 ? 0 : (kr0+7 >= S_ ? S_-1 : kr0+7);
            vreg0 = vp[(size_t)c0 * 1536]; vreg1 = vp[(size_t)c1 * 1536];
            vreg2 = vp[(size_t)c2 * 1536]; vreg3 = vp[(size_t)c3 * 1536];
            vreg4 = vp[(size_t)c4 * 1536]; vreg5 = vp[(size_t)c5 * 1536];
            vreg6 = vp[(size_t)c6 * 1536]; vreg7 = vp[(size_t)c7 * 1536];
        }
    };
    auto WRITE_LDS = [&](int buf) {
        *(s8v*)&Klds[buf][ki * 64 + ((kss ^ (ki & 7)) * 8)] = kreg;
        union { s8v s; u16 u[8]; } vv;
        vv.u[0] = vreg0; vv.u[1] = vreg1; vv.u[2] = vreg2; vv.u[3] = vreg3;
        vv.u[4] = vreg4; vv.u[5] = vreg5; vv.u[6] = vreg6; vv.u[7] = vreg7;
        *(s8v*)&Vt[buf][vd * 64 + ((vkb ^ (vd & 7)) * 8)] = vv.s;
    };

    LOAD_REGS(0);
    WRITE_LDS(0);
    LOAD_REGS(1);

    #pragma unroll 1
    for (int c = 0; c < 10; ++c) {
        asm volatile("s_waitcnt lgkmcnt(0)" ::: "memory");
        __builtin_amdgcn_s_barrier();
        __builtin_amdgcn_sched_barrier(0);
        const int kc = q0 - 256 + c * 64;
        const int buf = c & 1;

        #pragma unroll
        for (int sub = 0; sub < 2; ++sub) {
            const int kc2 = kc + sub * 32;
            if (kc2 + 31 < wq0 - 256 || kc2 > wq0 + 271) continue;

            f4v st[2] = {};
            __builtin_amdgcn_s_setprio(1);
            #pragma unroll
            for (int tt = 0; tt < 2; ++tt) {
                #pragma unroll
                for (int ks = 0; ks < 2; ++ks) {
                    const int row = sub * 32 + tt * 16 + lq;
                    const s8v af = *(const s8v*)&Klds[buf][row * 64 + (((ks * 4 + g) ^ (row & 7)) * 8)];
                    st[tt] = __builtin_amdgcn_mfma_f32_16x16x32_bf16(af, qf[ks], st[tt], 0, 0, 0);
                }
            }
            __builtin_amdgcn_s_setprio(0);

            float psum = 0.f;
            unsigned wpk[2][2];
            #pragma unroll
            for (int tt = 0; tt < 2; ++tt) {
                float pr[4];
                #pragma unroll
                for (int r = 0; r < 4; ++r) {
                    const int off = kc2 + 16 * tt + r + oblane;
                    float e = __expf(fminf(st[tt][r], 60.f)) *
                              padfa[c * 64 + sub * 32 + 16 * tt + 4 * g + r];
                    pr[r] = ((unsigned)off <= 512u) ? e : 0.f;
                    psum += pr[r];
                }
                wpk[tt][0] = pack2bf(pr[0], pr[1]);
                wpk[tt][1] = pack2bf(pr[2], pr[3]);
            }
            psum += __shfl_xor(psum, 16);
            psum += __shfl_xor(psum, 32);
            lsum += psum;

            const int srcA = (((2 * g) & 3) * 16 + lq) << 2;
            const int srcB = (((2 * g + 1) & 3) * 16 + lq) << 2;
            const bool hi = (g >= 2);
            union { s8v s; int u[4]; } pa;
            {
                int a0 = __builtin_amdgcn_ds_bpermute(srcA, (int)wpk[0][0]);
                int a1 = __builtin_amdgcn_ds_bpermute(srcA, (int)wpk[1][0]);
                pa.u[0] = hi ? a1 : a0;
                int b0 = __builtin_amdgcn_ds_bpermute(srcA, (int)wpk[0][1]);
                int b1 = __builtin_amdgcn_ds_bpermute(srcA, (int)wpk[1][1]);
                pa.u[1] = hi ? b1 : b0;
                int c0 = __builtin_amdgcn_ds_bpermute(srcB, (int)wpk[0][0]);
                int c1 = __builtin_amdgcn_ds_bpermute(srcB, (int)wpk[1][0]);
                pa.u[2] = hi ? c1 : c0;
                int d0 = __builtin_amdgcn_ds_bpermute(srcB, (int)wpk[0][1]);
                int d1 = __builtin_amdgcn_ds_bpermute(srcB, (int)wpk[1][1]);
                pa.u[3] = hi ? d1 : d0;
            }

            __builtin_amdgcn_s_setprio(1);
            #pragma unroll
            for (int dt = 0; dt < 4; ++dt) {
                const int row = dt * 16 + lq;
                const s8v vf = *(const s8v*)&Vt[buf][row * 64 + (((sub * 4 + g) ^ (row & 7)) * 8)];
                oacc[dt] = __builtin_amdgcn_mfma_f32_16x16x32_bf16(pa.s, vf, oacc[dt], 0, 0, 0);
            }
            __builtin_amdgcn_s_setprio(0);
        }

        if (c + 1 < 10) WRITE_LDS((c + 1) & 1);
        if (c + 2 < 10) LOAD_REGS(c + 2);
    }

    float inv = 1.0f / lsum;
    #pragma unroll
    for (int r = 0; r < 4; ++r) {
        int iv = __builtin_amdgcn_ds_bpermute((4 * g + r) << 2, __float_as_int(inv));
        float invq = __int_as_float(iv);
        const int qq = wq0 + 4 * g + r;
        __hip_bfloat16* orow = o + ((size_t)b * S_ + qq) * 512 + h * 64;
        #pragma unroll
        for (int dt = 0; dt < 4; ++dt)
            orow[dt * 16 + lq] = __float2bfloat16(oacc[dt][r] * invq);
    }

    // rare path: pad[q]==0 -> plain softmax over ALL S keys (overwrites)
    {
        int padq = pad[b * S_ + wq0 + lq];
        unsigned long long bal = __ballot(g == 0 && padq == 0);
        if (bal) {
            #pragma unroll 1
            for (int r = 0; r < 16; ++r) {
                if (!((bal >> r) & 1ull)) continue;
                const int qq = wq0 + r;
                const float qd = bf2f(qkv[base + (size_t)qq * 1536 + lane]);
                float ls = 0.f, av = 0.f;
                #pragma unroll 1
                for (int s = 0; s < S_; ++s) {
                    float xp = qd * bf2f(qkv[base + 512 + (size_t)s * 1536 + lane]);
                    #pragma unroll
                    for (int m = 32; m; m >>= 1) xp += __shfl_xor(xp, m);
                    float p = __expf(fminf(xp, 60.f));
                    ls += p;
                    av += p * bf2f(qkv[base + 1024 + (size_t)s * 1536 + lane]);
                }
                o[((size_t)b * S_ + qq) * 512 + h * 64 + lane] = __float2bfloat16(av / ls);
            }
        }
    }
}

// ---------------------------------------------------------------------------
extern "C" void kernel_launch(void* const* d_in, const int* in_sizes, int n_in,
                              void* d_out, int out_size, void* d_ws, size_t ws_size,
                              hipStream_t stream)
{
    const int*   tok   = (const int*)  d_in[0];
    const float* emb   = (const float*)d_in[1];
    const float* wq    = (const float*)d_in[2];
    const float* wk    = (const float*)d_in[3];
    const float* wv    = (const float*)d_in[4];
    const float* wo    = (const float*)d_in[5];
    const float* ln1_s = (const float*)d_in[6];
    const float* ln1_b = (const float*)d_in[7];
    const float* ln2_s = (const float*)d_in[8];
    const float* ln2_b = (const float*)d_in[9];
    const float* w1    = (const float*)d_in[10];
    const float* b1    = (const float*)d_in[11];
    const float* w2    = (const float*)d_in[12];
    const float* b2    = (const float*)d_in[13];
    const float* lnf_s = (const float*)d_in[14];
    const float* lnf_b = (const float*)d_in[15];
    float* out = (float*)d_out;

    char* ws = (char*)d_ws;
    u16*            x     = (u16*)(ws + 0);                      //  4.19 MB bf16
    __hip_bfloat16* ybf   = (__hip_bfloat16*)(ws + 8388608);     //  4.19 MB bf16
    __hip_bfloat16* qkvbf = (__hip_bfloat16*)(ws + 12582912);    // 12.58 MB bf16
    __hip_bfloat16* ob    = (__hip_bfloat16*)(ws + 37748736);    //  4.19 MB bf16
    __hip_bfloat16* hb    = (__hip_bfloat16*)(ws + 41943040);    // 16.78 MB bf16
    int*            pad   = (int*)(ws + 58720256);               // 16 KB
    __hip_bfloat16* wT    = (__hip_bfloat16*)(ws + 58736640);    // 37.75 MB

    const int NT = B_ * S_;   // 4096

    startup_kernel<<<22528, 256, 0, stream>>>(tok, emb, wq, wk, wv, wo, w1, w2,
                                              wT, x, pad);

    for (int l = 0; l < L_; ++l) {
        __hip_bfloat16* wTl = wT + (size_t)l * 3145728;
        ln_kernel<true><<<NT / 4, 256, 0, stream>>>(x, ln1_s + l * D_, ln1_b + l * D_, (void*)ybf);
        // fused QKV: [4096x512] x [512x1536] -> qkvbf [4096][1536] bf16
        gemm_1g<0><<<768, 256, 0, stream>>>(ybf, wTl, nullptr, (void*)qkvbf,
                                            512, 1536, 24, 0);
        attn_mfma_kernel<<<dim3(16, 16), 512, 0, stream>>>((const u16*)qkvbf, pad, ob);
        gemm_bk64<1><<<256, 512, 0, stream>>>(ob, wTl + 786432, nullptr, x,
                                              x, 512, 512, 8, 0);
        ln_kernel<true><<<NT / 4, 256, 0, stream>>>(x, ln2_s + l * D_, ln2_b + l * D_, (void*)ybf);
        gemm_1g<2><<<1024, 256, 0, stream>>>(ybf, wTl + 1048576, b1 + l * M_,
                                             (void*)hb, 512, 2048, 32, 1);
        gemm_bk64<3><<<256, 512, 0, stream>>>(hb, wTl + 2097152, b2 + l * D_, x,
                                              x, 2048, 512, 8, 0);
    }
    ln_kernel<false><<<NT / 4, 256, 0, stream>>>(x, lnf_s, lnf_b, (void*)out);
}